// Round 9
// baseline (332.779 us; speedup 1.0000x reference)
//
#include <hip/hip_runtime.h>
#include <hip/hip_bf16.h>

typedef __attribute__((ext_vector_type(8))) short short8;
typedef __attribute__((ext_vector_type(4))) float f32x4;

#define MFMA16(a,b,c) __builtin_amdgcn_mfma_f32_16x16x32_bf16((a),(b),(c),0,0,0)

constexpr int Tt = 1705;          // (L+1) + L*16 + L*196
constexpr int Tp = 1792;          // padded to 28*64
constexpr int NKT_ALL = 28;       // Tp/64 key tiles
constexpr int NH = 12, HD = 64, Bb = 4, C_ = 768;
constexpr int M_  = Bb * Tt;      // 6820
constexpr int Mp  = 6912;         // 54*128
constexpr int NQT = 14;           // 128-row q-tiles
constexpr int NCH = 4;            // key-range chunks per q-tile (split-K flash)
constexpr float QSCALE = 0.18033688011116016f;   // (1/8) * log2(e)

__device__ __forceinline__ void gl16(const void* g, void* l) {
  __builtin_amdgcn_global_load_lds((const __attribute__((address_space(1))) void*)g,
                                   (__attribute__((address_space(3))) void*)l, 16, 0, 0);
}

// raw v_exp_f32 (no libm fixup). Inputs bounded; -1e30 -> 0.
__device__ __forceinline__ float ex2(float x) {
  float r; asm("v_exp_f32 %0, %1" : "=v"(r) : "v"(x)); return r;
}

// frame id of token t (t<1705). Action tokens (t<9) return their index.
__device__ __forceinline__ int frame_of(int t) {
  return t < 9 ? t : (t < 137 ? ((t - 9) >> 4) : ((t - 137) / 196));
}

// key-limit for a 16-row span starting at a (rows [a, a+15])
__device__ __forceinline__ int lim16(int a) {
  if (a >= Tt) return 0;
  int bnd = min(a + 15, Tt - 1);
  int fmax = (a == 0) ? 8 : frame_of(min(bnd, a < 137 ? 136 : bnd));
  return (fmax >= 8) ? Tt : 137 + (fmax + 1) * 196;
}

// ---------------- elementwise convert x fp32 -> bf16 (pad rows zeroed) -------
__global__ __launch_bounds__(256) void k_conv_x(const float* __restrict__ x,
                                                __hip_bfloat16* __restrict__ xb) {
  int i = blockIdx.x * 256 + threadIdx.x;       // one float4 per thread
  if (i >= Mp * C_ / 4) return;
  float4 v = make_float4(0.f, 0.f, 0.f, 0.f);
  if (i * 4 < M_ * C_) v = ((const float4*)x)[i];
  __hip_bfloat16 o0 = __float2bfloat16(v.x), o1 = __float2bfloat16(v.y),
                 o2 = __float2bfloat16(v.z), o3 = __float2bfloat16(v.w);
  ushort4 u = make_ushort4(*(unsigned short*)&o0, *(unsigned short*)&o1,
                           *(unsigned short*)&o2, *(unsigned short*)&o3);
  ((ushort4*)xb)[i] = u;
}

// ---------------- transpose+convert W (fp32 [K,N] -> bf16 [N,K]) -------------
__global__ __launch_bounds__(256) void k_transpose_w(const float* __restrict__ src,
                                                     __hip_bfloat16* __restrict__ dst,
                                                     int K, int N) {
  __shared__ float tile[32][33];
  int kb = blockIdx.x * 32, nb = blockIdx.y * 32;
  int tx = threadIdx.x & 31, ty = threadIdx.x >> 5;
  for (int i = 0; i < 4; i++)
    tile[ty + i * 8][tx] = src[(size_t)(kb + ty + i * 8) * N + nb + tx];
  __syncthreads();
  for (int i = 0; i < 4; i++)
    dst[(size_t)(nb + ty + i * 8) * K + kb + tx] = __float2bfloat16(tile[tx][ty + i * 8]);
}

// ---------------- m97-style 128x128 bf16 GEMM core (B^T input) ---------------
__device__ __forceinline__ void gemm_tile_bt(const __hip_bfloat16* A,
                                             const __hip_bfloat16* Bt,
                                             int K, int m0, int n0,
                                             __hip_bfloat16* As, __hip_bfloat16* Bs,
                                             f32x4 acc[4][4]) {
  const int tid = threadIdx.x;
  const int lane = tid & 63, w = tid >> 6;
  const int wy = w >> 1, wx = w & 1;
  const int l16 = lane & 15, grp = lane >> 4;
  for (int i = 0; i < 4; i++)
    for (int j = 0; j < 4; j++) { f32x4 z = {0.f,0.f,0.f,0.f}; acc[i][j] = z; }
  for (int k0 = 0; k0 < K; k0 += 32) {
    __syncthreads();
    for (int rr = 0; rr < 2; rr++) {
      int idx = rr * 256 + tid;
      int row = idx >> 2;
      int c8 = (idx & 3) ^ ((row >> 1) & 3);
      gl16(A  + (size_t)(m0 + row) * K + k0 + c8 * 8, As + idx * 8);
      gl16(Bt + (size_t)(n0 + row) * K + k0 + c8 * 8, Bs + idx * 8);
    }
    __syncthreads();
    short8 a[4], b[4];
    for (int i = 0; i < 4; i++) {
      int row = wy * 64 + i * 16 + l16;
      a[i] = *(const short8*)(As + row * 32 + ((grp ^ ((row >> 1) & 3)) * 8));
    }
    for (int j = 0; j < 4; j++) {
      int row = wx * 64 + j * 16 + l16;
      b[j] = *(const short8*)(Bs + row * 32 + ((grp ^ ((row >> 1) & 3)) * 8));
    }
    for (int i = 0; i < 4; i++)
      for (int j = 0; j < 4; j++)
        acc[i][j] = MFMA16(a[i], b[j], acc[i][j]);
  }
}

// qkv GEMM; q stored [bh][Tp][64] (pre-scaled); K and V scattered directly
// into MFMA-fragment-packed layouts so k_attn frag loads are coalesced 16B.
__global__ __launch_bounds__(256) void k_gemm_qkv(const __hip_bfloat16* __restrict__ xb,
                                                  const __hip_bfloat16* __restrict__ wat,
                                                  __hip_bfloat16* __restrict__ q,
                                                  __hip_bfloat16* __restrict__ kpk,
                                                  __hip_bfloat16* __restrict__ vpk) {
  __shared__ __hip_bfloat16 As[128 * 32], Bs[128 * 32];
  f32x4 acc[4][4];
  int m0 = blockIdx.x * 128, n0 = blockIdx.y * 128;
  gemm_tile_bt(xb, wat, C_, m0, n0, As, Bs, acc);
  const int lane = threadIdx.x & 63, w = threadIdx.x >> 6;
  const int wy = w >> 1, wx = w & 1;
  const int l16 = lane & 15, grp = lane >> 4;
  for (int i = 0; i < 4; i++)
    for (int r = 0; r < 4; r++) {
      int m = m0 + wy * 64 + i * 16 + grp * 4 + r;
      if (m >= M_) continue;
      int b = m / Tt, t = m - b * Tt;
      for (int j = 0; j < 4; j++) {
        int n = n0 + wx * 64 + j * 16 + l16;
        int which = n / C_;
        int c = n - which * C_;
        int h = c >> 6, d = c & 63;
        float val = acc[i][j][r];
        int bh = b * NH + h;
        if (which == 0) {
          q[((size_t)bh * Tp + t) * HD + d] = __float2bfloat16(val * QSCALE);
        } else if (which == 1) {
          int kt = t >> 6, jj = (t >> 4) & 3, mm = t & 15;
          int half = d >> 5, gg = (d >> 3) & 3, ss = d & 7;
          kpk[(((size_t)bh * NKT_ALL + kt) * 8 + jj * 2 + half) * 512 +
              (gg * 16 + mm) * 8 + ss] = __float2bfloat16(val);
        } else {
          int kt = t >> 6, kb2 = (t >> 5) & 1, k32 = t & 31;
          int gg = (k32 >> 2) & 3, ss = (k32 & 3) + ((k32 >> 4) & 1) * 4;
          int jt = d >> 4, mm = d & 15;
          vpk[(((size_t)bh * NKT_ALL + kt) * 8 + jt * 2 + kb2) * 512 +
              (gg * 16 + mm) * 8 + ss] = __float2bfloat16(val);
        }
      }
    }
}

// ---------------- 64x128-tile proj GEMM (2x the blocks of 128x128) -----------
__global__ __launch_bounds__(256) void k_gemm_proj64(const __hip_bfloat16* __restrict__ A,
                                                     const __hip_bfloat16* __restrict__ Bt,
                                                     float* __restrict__ out) {
  __shared__ __hip_bfloat16 As[64 * 32], Bs[128 * 32];
  const int tid = threadIdx.x;
  const int lane = tid & 63, w = tid >> 6;
  const int l16 = lane & 15, grp = lane >> 4;
  const int m0 = blockIdx.x * 64, n0 = blockIdx.y * 128;
  f32x4 acc[8];
  for (int j = 0; j < 8; j++) { f32x4 z = {0.f,0.f,0.f,0.f}; acc[j] = z; }
  for (int k0 = 0; k0 < C_; k0 += 32) {
    __syncthreads();
    {                                            // stage A 64x32 (1 chunk/thr)
      int row = tid >> 2;
      int c8 = (tid & 3) ^ ((row >> 1) & 3);
      gl16(A + (size_t)(m0 + row) * C_ + k0 + c8 * 8, As + tid * 8);
    }
    for (int rr = 0; rr < 2; rr++) {             // stage B^T 128x32
      int idx = rr * 256 + tid;
      int row = idx >> 2;
      int c8 = (idx & 3) ^ ((row >> 1) & 3);
      gl16(Bt + (size_t)(n0 + row) * C_ + k0 + c8 * 8, Bs + idx * 8);
    }
    __syncthreads();
    int arow = w * 16 + l16;
    short8 a = *(const short8*)(As + arow * 32 + ((grp ^ ((arow >> 1) & 3)) * 8));
    for (int j = 0; j < 8; j++) {
      int brow = j * 16 + l16;
      short8 b = *(const short8*)(Bs + brow * 32 + ((grp ^ ((brow >> 1) & 3)) * 8));
      acc[j] = MFMA16(a, b, acc[j]);
    }
  }
  for (int r = 0; r < 4; r++) {
    int m = m0 + w * 16 + grp * 4 + r;
    if (m >= M_) continue;
    for (int j = 0; j < 8; j++)
      out[(size_t)m * C_ + n0 + j * 16 + l16] = acc[j][r];
  }
}

// ---------------- barrier-free, LDS-free split-K flash attention -------------
// R8 skeleton + VALU diet: raw v_exp_f32, threshold-compare mask (A/B/C per
// lane, no integer division per key), deferred softmax-sum reduction.
union S8u { short8 v; struct { unsigned long long lo, hi; } q; unsigned u[4]; };

__device__ __forceinline__ unsigned pack2bf(float a, float b) {
  union { __hip_bfloat162 h; unsigned u; } cv;
  cv.h = __float22bfloat162_rn(make_float2(a, b));
  return cv.u;
}

__global__ __launch_bounds__(256, 4) void k_attn(const __hip_bfloat16* __restrict__ q,
                                                 const __hip_bfloat16* __restrict__ kpk,
                                                 const __hip_bfloat16* __restrict__ vpk,
                                                 __hip_bfloat16* __restrict__ Opart,
                                                 float* __restrict__ lpart) {
  const int tid = threadIdx.x, lane = tid & 63, w = tid >> 6;
  const int l16 = lane & 15, grp = lane >> 4;
  // XCD-aware decode: id = (bh&7) + 8*(cq + 56*(bh>>3))
  const int id = blockIdx.x;
  const int xslot = id & 7, rr_ = id >> 3;
  const int bh = xslot + 8 * (rr_ / 56);
  const int cq = rr_ % 56;                      // qt*NCH + ch
  const int qt = cq >> 2, ch = cq & (NCH - 1);
  const int t0q = qt * 128;
  const __hip_bfloat16* qb = q + (size_t)bh * Tp * HD;

  int lim[2], Cmn[2], Ath[2], Bth[2], Cth[2];
  for (int g = 0; g < 2; g++) {
    int a = t0q + w * 32 + g * 16;
    lim[g] = lim16(a);
    int fqmn, fql;
    if (a >= Tt) { fqmn = 8; fql = 8; }
    else {
      int bnd = min(a + 15, Tt - 1);
      fqmn = min(frame_of(a), frame_of(bnd));
      int t = a + l16;
      fql = (t >= Tt) ? 8 : frame_of(t);
    }
    Cmn[g] = min(137 + 196 * (fqmn + 1), Tt);   // wave-wide full-tile bound
    Ath[g] = fql + 2;                            // action keys: key < A
    Bth[g] = 9 + 16 * (fql + 1);                 // tactile keys: key < B
    Cth[g] = min(137 + 196 * (fql + 1), Tt);     // image keys: key < C
  }
  int limw = max(lim[0], lim[1]);
  int nktw = (limw + 63) >> 6;                  // this wave's needed tiles
  int k0t = (ch * nktw) >> 2;                   // balanced split
  int k1t = ((ch + 1) * nktw) >> 2;

  // Q fragments (once per wave)
  short8 qa[2][2];
  for (int g = 0; g < 2; g++) {
    const __hip_bfloat16* qr = qb + (size_t)(t0q + w * 32 + g * 16 + l16) * HD + grp * 8;
    qa[g][0] = *(const short8*)(qr);
    qa[g][1] = *(const short8*)(qr + 32);
  }
  f32x4 o[2][4];
  for (int g = 0; g < 2; g++)
    for (int jt = 0; jt < 4; jt++) { f32x4 z = {0.f,0.f,0.f,0.f}; o[g][jt] = z; }
  f32x4 ps[2];
  { f32x4 z = {0.f,0.f,0.f,0.f}; ps[0] = z; ps[1] = z; }

  const short8* kbase = (const short8*)(kpk + (size_t)bh * NKT_ALL * 4096);
  const short8* vbase = (const short8*)(vpk + (size_t)bh * NKT_ALL * 4096);

  for (int kt = k0t; kt < k1t; kt++) {
    const int t0k = kt * 64;
    const short8* kp = kbase + (size_t)kt * 512;
    const short8* vp = vbase + (size_t)kt * 512;
    short8 kf[4][2], vf[4][2];
    for (int j = 0; j < 4; j++)
      for (int hh = 0; hh < 2; hh++) kf[j][hh] = kp[(j * 2 + hh) * 64 + lane];
    for (int jt = 0; jt < 4; jt++)
      for (int kb2 = 0; kb2 < 2; kb2++) vf[jt][kb2] = vp[(jt * 2 + kb2) * 64 + lane];

    f32x4 s[2][4];
    for (int j = 0; j < 4; j++) {               // S^T = K * Q^T
      f32x4 z = {0.f,0.f,0.f,0.f};
      s[0][j] = MFMA16(kf[j][0], qa[0][0], z);
      s[0][j] = MFMA16(kf[j][1], qa[0][1], s[0][j]);
      s[1][j] = MFMA16(kf[j][0], qa[1][0], z);
      s[1][j] = MFMA16(kf[j][1], qa[1][1], s[1][j]);
    }

    bool act0 = t0k < lim[0], act1 = t0k < lim[1];
    bool fullk = (t0k + 64 <= Tt);
    S8u pf[2][2];
    for (int g = 0; g < 2; g++) {
      bool act = g == 0 ? act0 : act1;
      if (!act) continue;                       // wave-uniform
      bool needm = !(fullk && (t0k >= 192 ? (t0k + 64) <= Cmn[g] : Cmn[g] >= Tt));
      if (needm) {                              // threshold-compare mask
        for (int j = 0; j < 4; j++)
          for (int r = 0; r < 4; r++) {
            int key = t0k + j * 16 + grp * 4 + r;
            int thr = key < 9 ? Ath[g] : (key < 137 ? Bth[g] : Cth[g]);
            if (key >= thr) s[g][j][r] = -1e30f;
          }
      }
      f32x4 p[4];
      for (int j = 0; j < 4; j++)
        for (int r = 0; r < 4; r++) p[j][r] = ex2(s[g][j][r]);
      ps[g] += (p[0] + p[1]) + (p[2] + p[3]);   // deferred reduction
      pf[g][0].u[0] = pack2bf(p[0][0], p[0][1]);
      pf[g][0].u[1] = pack2bf(p[0][2], p[0][3]);
      pf[g][0].u[2] = pack2bf(p[1][0], p[1][1]);
      pf[g][0].u[3] = pack2bf(p[1][2], p[1][3]);
      pf[g][1].u[0] = pack2bf(p[2][0], p[2][1]);
      pf[g][1].u[1] = pack2bf(p[2][2], p[2][3]);
      pf[g][1].u[2] = pack2bf(p[3][0], p[3][1]);
      pf[g][1].u[3] = pack2bf(p[3][2], p[3][3]);
    }

    for (int jt = 0; jt < 4; jt++)              // O^T += V^T * P^T
      for (int kb2 = 0; kb2 < 2; kb2++) {
        if (act0) o[0][jt] = MFMA16(vf[jt][kb2], pf[0][kb2].v, o[0][jt]);
        if (act1) o[1][jt] = MFMA16(vf[jt][kb2], pf[1][kb2].v, o[1][jt]);
      }
  }

  // final softmax-denominator reduction (once, not per tile)
  float lr[2];
  for (int g = 0; g < 2; g++) {
    float sum = (ps[g][0] + ps[g][1]) + (ps[g][2] + ps[g][3]);
    sum += __shfl_xor(sum, 16);
    sum += __shfl_xor(sum, 32);
    lr[g] = sum;
  }

  // epilogue: unnormalized bf16 partials (always written, zeros if empty)
  const int blk = bh * (NQT * NCH) + cq;
  __hip_bfloat16* op = Opart + (size_t)blk * (128 * 64);
  for (int g = 0; g < 2; g++) {
    int row = w * 32 + g * 16 + l16;
    for (int jt = 0; jt < 4; jt++) {
      unsigned p01 = pack2bf(o[g][jt][0], o[g][jt][1]);
      unsigned p23 = pack2bf(o[g][jt][2], o[g][jt][3]);
      ushort4 u;
      u.x = p01 & 0xffff; u.y = p01 >> 16; u.z = p23 & 0xffff; u.w = p23 >> 16;
      *(ushort4*)(op + row * 64 + jt * 16 + grp * 4) = u;
    }
    if (grp == 0) lpart[(size_t)blk * 128 + w * 32 + g * 16 + l16] = lr[g];
  }
}

// sum NCH chunk partials, normalize, write y bf16
__global__ __launch_bounds__(256) void k_combine(const __hip_bfloat16* __restrict__ Opart,
                                                 const float* __restrict__ lpart,
                                                 __hip_bfloat16* __restrict__ y) {
  const int tid = threadIdx.x;
  const int qt = blockIdx.x, bh = blockIdx.y;
  const int b = bh / NH, h = bh - b * NH;
  const int t0q = qt * 128;
  const int blk0 = bh * (NQT * NCH) + qt * NCH;
  __shared__ float ls[128];
  if (tid < 128) {
    float s = 0.f;
    for (int c = 0; c < NCH; c++) s += lpart[(size_t)(blk0 + c) * 128 + tid];
    ls[tid] = (s > 0.f) ? 1.0f / s : 0.f;
  }
  __syncthreads();
  for (int it = 0; it < 4; it++) {
    int e8 = it * 256 + tid;                     // 8-elem group in [0,1024)
    int e = e8 * 8;
    int row = e >> 6, d = e & 63;
    int t = t0q + row;
    if (t >= Tt) continue;
    float acc[8] = {0,0,0,0,0,0,0,0};
    for (int c = 0; c < NCH; c++) {
      short8 vv = *(const short8*)(Opart + (size_t)(blk0 + c) * (128 * 64) + e);
      for (int i = 0; i < 8; i++) {
        union { unsigned u; float f; } cv;
        cv.u = ((unsigned)(unsigned short)vv[i]) << 16;
        acc[i] += cv.f;
      }
    }
    float rinv = ls[row];
    short8 outv;
    for (int i = 0; i < 8; i += 2) {
      unsigned p = pack2bf(acc[i] * rinv, acc[i + 1] * rinv);
      outv[i] = (short)(p & 0xffff);
      outv[i + 1] = (short)(p >> 16);
    }
    *(short8*)(y + (size_t)(b * Tt + t) * C_ + h * 64 + d) = outv;
  }
}

extern "C" void kernel_launch(void* const* d_in, const int* in_sizes, int n_in,
                              void* d_out, int out_size, void* d_ws, size_t ws_size,
                              hipStream_t stream) {
  const float* x  = (const float*)d_in[0];
  const float* Wa = (const float*)d_in[1];
  const float* Wp = (const float*)d_in[2];
  float* out = (float*)d_out;

  char* ws = (char*)d_ws;
  size_t off = 0;
  auto alloc = [&](size_t bytes) { size_t r = off; off += (bytes + 255) & ~(size_t)255; return r; };
  __hip_bfloat16* xb  = (__hip_bfloat16*)(ws + alloc((size_t)Mp * C_ * 2));
  __hip_bfloat16* wat = (__hip_bfloat16*)(ws + alloc((size_t)3 * C_ * C_ * 2));
  __hip_bfloat16* wpt = (__hip_bfloat16*)(ws + alloc((size_t)C_ * C_ * 2));
  __hip_bfloat16* qb  = (__hip_bfloat16*)(ws + alloc((size_t)Bb * NH * Tp * HD * 2));
  __hip_bfloat16* kpk = (__hip_bfloat16*)(ws + alloc((size_t)Bb * NH * NKT_ALL * 4096 * 2));
  __hip_bfloat16* vpk = (__hip_bfloat16*)(ws + alloc((size_t)Bb * NH * NKT_ALL * 4096 * 2));
  __hip_bfloat16* yb  = (__hip_bfloat16*)(ws + alloc((size_t)Mp * C_ * 2));
  __hip_bfloat16* Opart = (__hip_bfloat16*)(ws + alloc((size_t)Bb * NH * NQT * NCH * 128 * 64 * 2));
  float*          lpart = (float*)(ws + alloc((size_t)Bb * NH * NQT * NCH * 128 * 4));

  k_conv_x<<<(Mp * C_ / 4 + 255) / 256, 256, 0, stream>>>(x, xb);
  k_transpose_w<<<dim3(C_ / 32, 3 * C_ / 32), 256, 0, stream>>>(Wa, wat, C_, 3 * C_);
  k_transpose_w<<<dim3(C_ / 32, C_ / 32), 256, 0, stream>>>(Wp, wpt, C_, C_);
  k_gemm_qkv<<<dim3(Mp / 128, 3 * C_ / 128), 256, 0, stream>>>(xb, wat, qb, kpk, vpk);
  k_attn<<<dim3(Bb * NH * NQT * NCH), 256, 0, stream>>>(qb, kpk, vpk, Opart, lpart);
  k_combine<<<dim3(NQT, Bb * NH), 256, 0, stream>>>(Opart, lpart, yb);
  k_gemm_proj64<<<dim3(Mp / 64, C_ / 128), 256, 0, stream>>>(yb, wpt, out);
}

// Round 10
// 224.904 us; speedup vs baseline: 1.4797x; 1.4797x over previous
//
#include <hip/hip_runtime.h>
#include <hip/hip_bf16.h>

typedef __attribute__((ext_vector_type(8))) short short8;
typedef __attribute__((ext_vector_type(4))) float f32x4;

#define MFMA16(a,b,c) __builtin_amdgcn_mfma_f32_16x16x32_bf16((a),(b),(c),0,0,0)

constexpr int Tt = 1705;          // (L+1) + L*16 + L*196
constexpr int Tp = 1792;          // padded to 28*64
constexpr int NKT_ALL = 28;       // Tp/64 key tiles
constexpr int NH = 12, HD = 64, Bb = 4, C_ = 768;
constexpr int M_  = Bb * Tt;      // 6820
constexpr int Mp  = 6912;         // 54*128
constexpr int NQT = 14;           // 128-row q-tiles
constexpr int NCH = 4;            // key-range chunks per q-tile (split-K flash)
constexpr float QSCALE = 0.18033688011116016f;   // (1/8) * log2(e)

__device__ __forceinline__ void gl16(const void* g, void* l) {
  __builtin_amdgcn_global_load_lds((const __attribute__((address_space(1))) void*)g,
                                   (__attribute__((address_space(3))) void*)l, 16, 0, 0);
}

// raw v_exp_f32 (no libm fixup). Inputs bounded; -1e30 -> 0.
__device__ __forceinline__ float ex2(float x) {
  float r; asm("v_exp_f32 %0, %1" : "=v"(r) : "v"(x)); return r;
}

// frame id of token t (t<1705). Action tokens (t<9) return their index.
__device__ __forceinline__ int frame_of(int t) {
  return t < 9 ? t : (t < 137 ? ((t - 9) >> 4) : ((t - 137) / 196));
}

// key-limit for a 16-row span starting at a (rows [a, a+15])
__device__ __forceinline__ int lim16(int a) {
  if (a >= Tt) return 0;
  int bnd = min(a + 15, Tt - 1);
  int fmax = (a == 0) ? 8 : frame_of(min(bnd, a < 137 ? 136 : bnd));
  return (fmax >= 8) ? Tt : 137 + (fmax + 1) * 196;
}

// ---------------- elementwise convert x fp32 -> bf16 (pad rows zeroed) -------
__global__ __launch_bounds__(256) void k_conv_x(const float* __restrict__ x,
                                                __hip_bfloat16* __restrict__ xb) {
  int i = blockIdx.x * 256 + threadIdx.x;       // one float4 per thread
  if (i >= Mp * C_ / 4) return;
  float4 v = make_float4(0.f, 0.f, 0.f, 0.f);
  if (i * 4 < M_ * C_) v = ((const float4*)x)[i];
  __hip_bfloat16 o0 = __float2bfloat16(v.x), o1 = __float2bfloat16(v.y),
                 o2 = __float2bfloat16(v.z), o3 = __float2bfloat16(v.w);
  ushort4 u = make_ushort4(*(unsigned short*)&o0, *(unsigned short*)&o1,
                           *(unsigned short*)&o2, *(unsigned short*)&o3);
  ((ushort4*)xb)[i] = u;
}

// ---------------- transpose+convert W (fp32 [K,N] -> bf16 [N,K]) -------------
__global__ __launch_bounds__(256) void k_transpose_w(const float* __restrict__ src,
                                                     __hip_bfloat16* __restrict__ dst,
                                                     int K, int N) {
  __shared__ float tile[32][33];
  int kb = blockIdx.x * 32, nb = blockIdx.y * 32;
  int tx = threadIdx.x & 31, ty = threadIdx.x >> 5;
  for (int i = 0; i < 4; i++)
    tile[ty + i * 8][tx] = src[(size_t)(kb + ty + i * 8) * N + nb + tx];
  __syncthreads();
  for (int i = 0; i < 4; i++)
    dst[(size_t)(nb + ty + i * 8) * K + kb + tx] = __float2bfloat16(tile[tx][ty + i * 8]);
}

// ---------------- m97-style 128x128 bf16 GEMM core (B^T input) ---------------
__device__ __forceinline__ void gemm_tile_bt(const __hip_bfloat16* A,
                                             const __hip_bfloat16* Bt,
                                             int K, int m0, int n0,
                                             __hip_bfloat16* As, __hip_bfloat16* Bs,
                                             f32x4 acc[4][4]) {
  const int tid = threadIdx.x;
  const int lane = tid & 63, w = tid >> 6;
  const int wy = w >> 1, wx = w & 1;
  const int l16 = lane & 15, grp = lane >> 4;
  for (int i = 0; i < 4; i++)
    for (int j = 0; j < 4; j++) { f32x4 z = {0.f,0.f,0.f,0.f}; acc[i][j] = z; }
  for (int k0 = 0; k0 < K; k0 += 32) {
    __syncthreads();
    for (int rr = 0; rr < 2; rr++) {
      int idx = rr * 256 + tid;
      int row = idx >> 2;
      int c8 = (idx & 3) ^ ((row >> 1) & 3);
      gl16(A  + (size_t)(m0 + row) * K + k0 + c8 * 8, As + idx * 8);
      gl16(Bt + (size_t)(n0 + row) * K + k0 + c8 * 8, Bs + idx * 8);
    }
    __syncthreads();
    short8 a[4], b[4];
    for (int i = 0; i < 4; i++) {
      int row = wy * 64 + i * 16 + l16;
      a[i] = *(const short8*)(As + row * 32 + ((grp ^ ((row >> 1) & 3)) * 8));
    }
    for (int j = 0; j < 4; j++) {
      int row = wx * 64 + j * 16 + l16;
      b[j] = *(const short8*)(Bs + row * 32 + ((grp ^ ((row >> 1) & 3)) * 8));
    }
    for (int i = 0; i < 4; i++)
      for (int j = 0; j < 4; j++)
        acc[i][j] = MFMA16(a[i], b[j], acc[i][j]);
  }
}

// qkv GEMM; q stored [bh][Tp][64] (pre-scaled); K and V scattered directly
// into MFMA-fragment-packed layouts so k_attn frag loads are coalesced 16B.
__global__ __launch_bounds__(256) void k_gemm_qkv(const __hip_bfloat16* __restrict__ xb,
                                                  const __hip_bfloat16* __restrict__ wat,
                                                  __hip_bfloat16* __restrict__ q,
                                                  __hip_bfloat16* __restrict__ kpk,
                                                  __hip_bfloat16* __restrict__ vpk) {
  __shared__ __hip_bfloat16 As[128 * 32], Bs[128 * 32];
  f32x4 acc[4][4];
  int m0 = blockIdx.x * 128, n0 = blockIdx.y * 128;
  gemm_tile_bt(xb, wat, C_, m0, n0, As, Bs, acc);
  const int lane = threadIdx.x & 63, w = threadIdx.x >> 6;
  const int wy = w >> 1, wx = w & 1;
  const int l16 = lane & 15, grp = lane >> 4;
  for (int i = 0; i < 4; i++)
    for (int r = 0; r < 4; r++) {
      int m = m0 + wy * 64 + i * 16 + grp * 4 + r;
      if (m >= M_) continue;
      int b = m / Tt, t = m - b * Tt;
      for (int j = 0; j < 4; j++) {
        int n = n0 + wx * 64 + j * 16 + l16;
        int which = n / C_;
        int c = n - which * C_;
        int h = c >> 6, d = c & 63;
        float val = acc[i][j][r];
        int bh = b * NH + h;
        if (which == 0) {
          q[((size_t)bh * Tp + t) * HD + d] = __float2bfloat16(val * QSCALE);
        } else if (which == 1) {
          int kt = t >> 6, jj = (t >> 4) & 3, mm = t & 15;
          int half = d >> 5, gg = (d >> 3) & 3, ss = d & 7;
          kpk[(((size_t)bh * NKT_ALL + kt) * 8 + jj * 2 + half) * 512 +
              (gg * 16 + mm) * 8 + ss] = __float2bfloat16(val);
        } else {
          int kt = t >> 6, kb2 = (t >> 5) & 1, k32 = t & 31;
          int gg = (k32 >> 2) & 3, ss = (k32 & 3) + ((k32 >> 4) & 1) * 4;
          int jt = d >> 4, mm = d & 15;
          vpk[(((size_t)bh * NKT_ALL + kt) * 8 + jt * 2 + kb2) * 512 +
              (gg * 16 + mm) * 8 + ss] = __float2bfloat16(val);
        }
      }
    }
}

// ---------------- 64x128-tile proj GEMM (2x the blocks of 128x128) -----------
__global__ __launch_bounds__(256) void k_gemm_proj64(const __hip_bfloat16* __restrict__ A,
                                                     const __hip_bfloat16* __restrict__ Bt,
                                                     float* __restrict__ out) {
  __shared__ __hip_bfloat16 As[64 * 32], Bs[128 * 32];
  const int tid = threadIdx.x;
  const int lane = tid & 63, w = tid >> 6;
  const int l16 = lane & 15, grp = lane >> 4;
  const int m0 = blockIdx.x * 64, n0 = blockIdx.y * 128;
  f32x4 acc[8];
  for (int j = 0; j < 8; j++) { f32x4 z = {0.f,0.f,0.f,0.f}; acc[j] = z; }
  for (int k0 = 0; k0 < C_; k0 += 32) {
    __syncthreads();
    {                                            // stage A 64x32 (1 chunk/thr)
      int row = tid >> 2;
      int c8 = (tid & 3) ^ ((row >> 1) & 3);
      gl16(A + (size_t)(m0 + row) * C_ + k0 + c8 * 8, As + tid * 8);
    }
    for (int rr = 0; rr < 2; rr++) {             // stage B^T 128x32
      int idx = rr * 256 + tid;
      int row = idx >> 2;
      int c8 = (idx & 3) ^ ((row >> 1) & 3);
      gl16(Bt + (size_t)(n0 + row) * C_ + k0 + c8 * 8, Bs + idx * 8);
    }
    __syncthreads();
    int arow = w * 16 + l16;
    short8 a = *(const short8*)(As + arow * 32 + ((grp ^ ((arow >> 1) & 3)) * 8));
    for (int j = 0; j < 8; j++) {
      int brow = j * 16 + l16;
      short8 b = *(const short8*)(Bs + brow * 32 + ((grp ^ ((brow >> 1) & 3)) * 8));
      acc[j] = MFMA16(a, b, acc[j]);
    }
  }
  for (int r = 0; r < 4; r++) {
    int m = m0 + w * 16 + grp * 4 + r;
    if (m >= M_) continue;
    for (int j = 0; j < 8; j++)
      out[(size_t)m * C_ + n0 + j * 16 + l16] = acc[j][r];
  }
}

// ---------------- barrier-free, LDS-free split-K flash attention -------------
// R8 skeleton + VALU diet (raw v_exp_f32, threshold mask, deferred reduction)
// at the known-no-spill occupancy bound (256,2). R9's (256,4) capped VGPR at
// 64 and spilled 310 MB to scratch — do NOT raise the bound.
union S8u { short8 v; struct { unsigned long long lo, hi; } q; unsigned u[4]; };

__device__ __forceinline__ unsigned pack2bf(float a, float b) {
  union { __hip_bfloat162 h; unsigned u; } cv;
  cv.h = __float22bfloat162_rn(make_float2(a, b));
  return cv.u;
}

__global__ __launch_bounds__(256, 2) void k_attn(const __hip_bfloat16* __restrict__ q,
                                                 const __hip_bfloat16* __restrict__ kpk,
                                                 const __hip_bfloat16* __restrict__ vpk,
                                                 __hip_bfloat16* __restrict__ Opart,
                                                 float* __restrict__ lpart) {
  const int tid = threadIdx.x, lane = tid & 63, w = tid >> 6;
  const int l16 = lane & 15, grp = lane >> 4;
  // XCD-aware decode: id = (bh&7) + 8*(cq + 56*(bh>>3))
  const int id = blockIdx.x;
  const int xslot = id & 7, rr_ = id >> 3;
  const int bh = xslot + 8 * (rr_ / 56);
  const int cq = rr_ % 56;                      // qt*NCH + ch
  const int qt = cq >> 2, ch = cq & (NCH - 1);
  const int t0q = qt * 128;
  const __hip_bfloat16* qb = q + (size_t)bh * Tp * HD;

  int lim[2], Cmn[2], Ath[2], Bth[2], Cth[2];
  for (int g = 0; g < 2; g++) {
    int a = t0q + w * 32 + g * 16;
    lim[g] = lim16(a);
    int fqmn, fql;
    if (a >= Tt) { fqmn = 8; fql = 8; }
    else {
      int bnd = min(a + 15, Tt - 1);
      fqmn = min(frame_of(a), frame_of(bnd));
      int t = a + l16;
      fql = (t >= Tt) ? 8 : frame_of(t);
    }
    Cmn[g] = min(137 + 196 * (fqmn + 1), Tt);   // wave-wide full-tile bound
    Ath[g] = fql + 2;                            // action keys: key < A
    Bth[g] = 9 + 16 * (fql + 1);                 // tactile keys: key < B
    Cth[g] = min(137 + 196 * (fql + 1), Tt);     // image keys: key < C
  }
  int limw = max(lim[0], lim[1]);
  int nktw = (limw + 63) >> 6;                  // this wave's needed tiles
  int k0t = (ch * nktw) >> 2;                   // balanced split
  int k1t = ((ch + 1) * nktw) >> 2;

  // Q fragments (once per wave)
  short8 qa[2][2];
  for (int g = 0; g < 2; g++) {
    const __hip_bfloat16* qr = qb + (size_t)(t0q + w * 32 + g * 16 + l16) * HD + grp * 8;
    qa[g][0] = *(const short8*)(qr);
    qa[g][1] = *(const short8*)(qr + 32);
  }
  f32x4 o[2][4];
  for (int g = 0; g < 2; g++)
    for (int jt = 0; jt < 4; jt++) { f32x4 z = {0.f,0.f,0.f,0.f}; o[g][jt] = z; }
  f32x4 ps[2];
  { f32x4 z = {0.f,0.f,0.f,0.f}; ps[0] = z; ps[1] = z; }

  const short8* kbase = (const short8*)(kpk + (size_t)bh * NKT_ALL * 4096);
  const short8* vbase = (const short8*)(vpk + (size_t)bh * NKT_ALL * 4096);

  for (int kt = k0t; kt < k1t; kt++) {
    const int t0k = kt * 64;
    const short8* kp = kbase + (size_t)kt * 512;
    const short8* vp = vbase + (size_t)kt * 512;
    short8 kf[4][2], vf[4][2];
    for (int j = 0; j < 4; j++)
      for (int hh = 0; hh < 2; hh++) kf[j][hh] = kp[(j * 2 + hh) * 64 + lane];
    for (int jt = 0; jt < 4; jt++)
      for (int kb2 = 0; kb2 < 2; kb2++) vf[jt][kb2] = vp[(jt * 2 + kb2) * 64 + lane];

    f32x4 s[2][4];
    for (int j = 0; j < 4; j++) {               // S^T = K * Q^T
      f32x4 z = {0.f,0.f,0.f,0.f};
      s[0][j] = MFMA16(kf[j][0], qa[0][0], z);
      s[0][j] = MFMA16(kf[j][1], qa[0][1], s[0][j]);
      s[1][j] = MFMA16(kf[j][0], qa[1][0], z);
      s[1][j] = MFMA16(kf[j][1], qa[1][1], s[1][j]);
    }

    bool act0 = t0k < lim[0], act1 = t0k < lim[1];
    bool fullk = (t0k + 64 <= Tt);
    S8u pf[2][2];
    for (int g = 0; g < 2; g++) {
      bool act = g == 0 ? act0 : act1;
      if (!act) continue;                       // wave-uniform
      bool needm = !(fullk && (t0k >= 192 ? (t0k + 64) <= Cmn[g] : Cmn[g] >= Tt));
      if (needm) {                              // threshold-compare mask
        for (int j = 0; j < 4; j++)
          for (int r = 0; r < 4; r++) {
            int key = t0k + j * 16 + grp * 4 + r;
            int thr = key < 9 ? Ath[g] : (key < 137 ? Bth[g] : Cth[g]);
            if (key >= thr) s[g][j][r] = -1e30f;
          }
      }
      f32x4 p[4];
      for (int j = 0; j < 4; j++)
        for (int r = 0; r < 4; r++) p[j][r] = ex2(s[g][j][r]);
      ps[g] += (p[0] + p[1]) + (p[2] + p[3]);   // deferred reduction
      pf[g][0].u[0] = pack2bf(p[0][0], p[0][1]);
      pf[g][0].u[1] = pack2bf(p[0][2], p[0][3]);
      pf[g][0].u[2] = pack2bf(p[1][0], p[1][1]);
      pf[g][0].u[3] = pack2bf(p[1][2], p[1][3]);
      pf[g][1].u[0] = pack2bf(p[2][0], p[2][1]);
      pf[g][1].u[1] = pack2bf(p[2][2], p[2][3]);
      pf[g][1].u[2] = pack2bf(p[3][0], p[3][1]);
      pf[g][1].u[3] = pack2bf(p[3][2], p[3][3]);
    }

    for (int jt = 0; jt < 4; jt++)              // O^T += V^T * P^T
      for (int kb2 = 0; kb2 < 2; kb2++) {
        if (act0) o[0][jt] = MFMA16(vf[jt][kb2], pf[0][kb2].v, o[0][jt]);
        if (act1) o[1][jt] = MFMA16(vf[jt][kb2], pf[1][kb2].v, o[1][jt]);
      }
  }

  // final softmax-denominator reduction (once, not per tile)
  float lr[2];
  for (int g = 0; g < 2; g++) {
    float sum = (ps[g][0] + ps[g][1]) + (ps[g][2] + ps[g][3]);
    sum += __shfl_xor(sum, 16);
    sum += __shfl_xor(sum, 32);
    lr[g] = sum;
  }

  // epilogue: unnormalized bf16 partials (always written, zeros if empty)
  const int blk = bh * (NQT * NCH) + cq;
  __hip_bfloat16* op = Opart + (size_t)blk * (128 * 64);
  for (int g = 0; g < 2; g++) {
    int row = w * 32 + g * 16 + l16;
    for (int jt = 0; jt < 4; jt++) {
      unsigned p01 = pack2bf(o[g][jt][0], o[g][jt][1]);
      unsigned p23 = pack2bf(o[g][jt][2], o[g][jt][3]);
      ushort4 u;
      u.x = p01 & 0xffff; u.y = p01 >> 16; u.z = p23 & 0xffff; u.w = p23 >> 16;
      *(ushort4*)(op + row * 64 + jt * 16 + grp * 4) = u;
    }
    if (grp == 0) lpart[(size_t)blk * 128 + w * 32 + g * 16 + l16] = lr[g];
  }
}

// sum NCH chunk partials, normalize, write y bf16
__global__ __launch_bounds__(256) void k_combine(const __hip_bfloat16* __restrict__ Opart,
                                                 const float* __restrict__ lpart,
                                                 __hip_bfloat16* __restrict__ y) {
  const int tid = threadIdx.x;
  const int qt = blockIdx.x, bh = blockIdx.y;
  const int b = bh / NH, h = bh - b * NH;
  const int t0q = qt * 128;
  const int blk0 = bh * (NQT * NCH) + qt * NCH;
  __shared__ float ls[128];
  if (tid < 128) {
    float s = 0.f;
    for (int c = 0; c < NCH; c++) s += lpart[(size_t)(blk0 + c) * 128 + tid];
    ls[tid] = (s > 0.f) ? 1.0f / s : 0.f;
  }
  __syncthreads();
  for (int it = 0; it < 4; it++) {
    int e8 = it * 256 + tid;                     // 8-elem group in [0,1024)
    int e = e8 * 8;
    int row = e >> 6, d = e & 63;
    int t = t0q + row;
    if (t >= Tt) continue;
    float acc[8] = {0,0,0,0,0,0,0,0};
    for (int c = 0; c < NCH; c++) {
      short8 vv = *(const short8*)(Opart + (size_t)(blk0 + c) * (128 * 64) + e);
      for (int i = 0; i < 8; i++) {
        union { unsigned u; float f; } cv;
        cv.u = ((unsigned)(unsigned short)vv[i]) << 16;
        acc[i] += cv.f;
      }
    }
    float rinv = ls[row];
    short8 outv;
    for (int i = 0; i < 8; i += 2) {
      unsigned p = pack2bf(acc[i] * rinv, acc[i + 1] * rinv);
      outv[i] = (short)(p & 0xffff);
      outv[i + 1] = (short)(p >> 16);
    }
    *(short8*)(y + (size_t)(b * Tt + t) * C_ + h * 64 + d) = outv;
  }
}

extern "C" void kernel_launch(void* const* d_in, const int* in_sizes, int n_in,
                              void* d_out, int out_size, void* d_ws, size_t ws_size,
                              hipStream_t stream) {
  const float* x  = (const float*)d_in[0];
  const float* Wa = (const float*)d_in[1];
  const float* Wp = (const float*)d_in[2];
  float* out = (float*)d_out;

  char* ws = (char*)d_ws;
  size_t off = 0;
  auto alloc = [&](size_t bytes) { size_t r = off; off += (bytes + 255) & ~(size_t)255; return r; };
  __hip_bfloat16* xb  = (__hip_bfloat16*)(ws + alloc((size_t)Mp * C_ * 2));
  __hip_bfloat16* wat = (__hip_bfloat16*)(ws + alloc((size_t)3 * C_ * C_ * 2));
  __hip_bfloat16* wpt = (__hip_bfloat16*)(ws + alloc((size_t)C_ * C_ * 2));
  __hip_bfloat16* qb  = (__hip_bfloat16*)(ws + alloc((size_t)Bb * NH * Tp * HD * 2));
  __hip_bfloat16* kpk = (__hip_bfloat16*)(ws + alloc((size_t)Bb * NH * NKT_ALL * 4096 * 2));
  __hip_bfloat16* vpk = (__hip_bfloat16*)(ws + alloc((size_t)Bb * NH * NKT_ALL * 4096 * 2));
  __hip_bfloat16* yb  = (__hip_bfloat16*)(ws + alloc((size_t)Mp * C_ * 2));
  __hip_bfloat16* Opart = (__hip_bfloat16*)(ws + alloc((size_t)Bb * NH * NQT * NCH * 128 * 64 * 2));
  float*          lpart = (float*)(ws + alloc((size_t)Bb * NH * NQT * NCH * 128 * 4));

  k_conv_x<<<(Mp * C_ / 4 + 255) / 256, 256, 0, stream>>>(x, xb);
  k_transpose_w<<<dim3(C_ / 32, 3 * C_ / 32), 256, 0, stream>>>(Wa, wat, C_, 3 * C_);
  k_transpose_w<<<dim3(C_ / 32, C_ / 32), 256, 0, stream>>>(Wp, wpt, C_, C_);
  k_gemm_qkv<<<dim3(Mp / 128, 3 * C_ / 128), 256, 0, stream>>>(xb, wat, qb, kpk, vpk);
  k_attn<<<dim3(Bb * NH * NQT * NCH), 256, 0, stream>>>(qb, kpk, vpk, Opart, lpart);
  k_combine<<<dim3(NQT, Bb * NH), 256, 0, stream>>>(Opart, lpart, yb);
  k_gemm_proj64<<<dim3(Mp / 64, C_ / 128), 256, 0, stream>>>(yb, wpt, out);
}